// Round 3
// baseline (231.773 us; speedup 1.0000x reference)
//
#include <hip/hip_runtime.h>
#include <hip/hip_bf16.h>

#define BATCH 4096
#define NEXP  16
#define DIN   2048
#define DOUT  2048

#define BM 128
#define BN 128
#define BK 64

typedef __attribute__((ext_vector_type(4))) float f32x4;
typedef __attribute__((ext_vector_type(8))) short bf16x8;

// --- Kernel 1: bucket sample indices by expert; write mxs/actions tail ---
__global__ void sort_kernel(const int* __restrict__ actions,
                            const float* __restrict__ mxs,
                            float* __restrict__ out_tail,   // d_out + BATCH*DOUT
                            int* __restrict__ offs,         // [NEXP+1]
                            int* __restrict__ sorted) {     // [BATCH]
    __shared__ int s_cnt[NEXP];
    __shared__ int s_cur[NEXP];
    const int tid = threadIdx.x;
    if (tid < NEXP) s_cnt[tid] = 0;
    __syncthreads();
    for (int i = tid; i < BATCH; i += blockDim.x) {
        int a = actions[i];
        atomicAdd(&s_cnt[a], 1);
        out_tail[i] = mxs[i];                    // mxs pass-through
        out_tail[BATCH + i] = (float)a;          // actions pass-through
    }
    __syncthreads();
    if (tid == 0) {
        int run = 0;
        for (int e = 0; e < NEXP; ++e) {
            offs[e] = run;
            s_cur[e] = run;
            run += s_cnt[e];
        }
        offs[NEXP] = run;
    }
    __syncthreads();
    // Bucket order is atomics-dependent, but each sample's output row is
    // computed independently (k-loop order fixed) -> output bit-deterministic.
    for (int i = tid; i < BATCH; i += blockDim.x) {
        int e = actions[i];
        int pos = atomicAdd(&s_cur[e], 1);
        sorted[pos] = i;
    }
}

// Split fp32 pair -> packed bf16 hi (bit-truncate) + bf16 lo (exact residual,
// bit-truncated). hi word = [bf16(x1) | bf16(x0)].
__device__ __forceinline__ void split_pair(float x0, float x1, unsigned& h, unsigned& l) {
    unsigned b0 = __float_as_uint(x0), b1 = __float_as_uint(x1);
    unsigned h0 = b0 & 0xFFFF0000u;
    unsigned h1 = b1 & 0xFFFF0000u;
    h = h1 | (b0 >> 16);
    unsigned l0 = __float_as_uint(x0 - __uint_as_float(h0));
    unsigned l1 = __float_as_uint(x1 - __uint_as_float(h1));
    l = (l1 & 0xFFFF0000u) | (l0 >> 16);
}

__device__ __forceinline__ void split8(const float* src, uint4& hi, uint4& lo) {
    f32x4 a = *(const f32x4*)src;
    f32x4 c = *(const f32x4*)(src + 4);
    split_pair(a.x, a.y, hi.x, lo.x);
    split_pair(a.z, a.w, hi.y, lo.y);
    split_pair(c.x, c.y, hi.z, lo.z);
    split_pair(c.z, c.w, hi.w, lo.w);
}

// LDS index for row r, 16B k-block kb (8 bf16), XOR-swizzled.
__device__ __forceinline__ int lidx(int r, int kb) {
    return r * BK + ((kb ^ (r & 7)) << 3);
}

// --- Kernel 2: grouped gather-GEMM, split-bf16 3-product MFMA ---
// grid = (DOUT/BN, NEXP, BATCH/BM); block = 256 (4 waves, 2x2 of 64x64)
__global__ __launch_bounds__(256, 2)
void gemm_kernel(const float* __restrict__ xs,
                 const float* __restrict__ W,
                 const float* __restrict__ bias,
                 const int* __restrict__ offs,
                 const int* __restrict__ sorted,
                 float* __restrict__ out) {
    __shared__ __align__(16) unsigned short Xhi[BM * BK];
    __shared__ __align__(16) unsigned short Xlo[BM * BK];
    __shared__ __align__(16) unsigned short Whi[BN * BK];
    __shared__ __align__(16) unsigned short Wlo[BN * BK];

    const int e = blockIdx.y;
    const int start = offs[e];
    const int cnt = offs[e + 1] - start;
    const int m0 = blockIdx.z * BM;
    if (m0 >= cnt) return;
    const int n0 = blockIdx.x * BN;

    const int tid = threadIdx.x;
    const int lane = tid & 63;
    const int wave = tid >> 6;
    const int wm = wave >> 1;      // wave row (0..1), 64 output rows each
    const int wn = wave & 1;       // wave col (0..1), 64 output cols each

    // staging role: row sr (+64 second pass), 16-float chunk kq
    const int sr = tid >> 2;       // 0..63
    const int kq = tid & 3;        // 0..3

    int xrow[2];
#pragma unroll
    for (int p = 0; p < 2; ++p) {
        int rm = m0 + sr + p * 64;
        xrow[p] = (rm < cnt) ? sorted[start + rm] : -1;
    }
    const float* wbase = W + ((size_t)e * DOUT + n0) * DIN;

    f32x4 acc[4][4];
#pragma unroll
    for (int i = 0; i < 4; ++i)
#pragma unroll
        for (int j = 0; j < 4; ++j) acc[i][j] = (f32x4){0.f, 0.f, 0.f, 0.f};

    for (int k0 = 0; k0 < DIN; k0 += BK) {
        // ---- stage X tile [BM][BK] as hi/lo bf16 ----
#pragma unroll
        for (int p = 0; p < 2; ++p) {
            int r = sr + p * 64;
            uint4 h0, l0, h1, l1;
            if (xrow[p] >= 0) {
                const float* src = xs + (size_t)xrow[p] * DIN + k0 + kq * 16;
                split8(src, h0, l0);
                split8(src + 8, h1, l1);
            } else {
                h0 = l0 = h1 = l1 = make_uint4(0u, 0u, 0u, 0u);
            }
            *(uint4*)&Xhi[lidx(r, 2 * kq)]     = h0;
            *(uint4*)&Xlo[lidx(r, 2 * kq)]     = l0;
            *(uint4*)&Xhi[lidx(r, 2 * kq + 1)] = h1;
            *(uint4*)&Xlo[lidx(r, 2 * kq + 1)] = l1;
        }
        // ---- stage W tile [BN][BK] as hi/lo bf16 ----
#pragma unroll
        for (int p = 0; p < 2; ++p) {
            int r = sr + p * 64;
            const float* src = wbase + (size_t)r * DIN + k0 + kq * 16;
            uint4 h0, l0, h1, l1;
            split8(src, h0, l0);
            split8(src + 8, h1, l1);
            *(uint4*)&Whi[lidx(r, 2 * kq)]     = h0;
            *(uint4*)&Wlo[lidx(r, 2 * kq)]     = l0;
            *(uint4*)&Whi[lidx(r, 2 * kq + 1)] = h1;
            *(uint4*)&Wlo[lidx(r, 2 * kq + 1)] = l1;
        }
        __syncthreads();

        const int g = lane >> 4;     // k-group 0..3
        const int rl = lane & 15;    // row-in-fragment
#pragma unroll
        for (int ks = 0; ks < 2; ++ks) {
            bf16x8 ah[4], al[4];
#pragma unroll
            for (int mi = 0; mi < 4; ++mi) {
                int R = wm * 64 + mi * 16 + rl;
                int idx = lidx(R, ks * 4 + g);
                ah[mi] = *(const bf16x8*)&Xhi[idx];
                al[mi] = *(const bf16x8*)&Xlo[idx];
            }
#pragma unroll
            for (int ni = 0; ni < 4; ++ni) {
                int R = wn * 64 + ni * 16 + rl;
                int idx = lidx(R, ks * 4 + g);
                bf16x8 bh = *(const bf16x8*)&Whi[idx];
                bf16x8 bl = *(const bf16x8*)&Wlo[idx];
#pragma unroll
                for (int mi = 0; mi < 4; ++mi) {
                    acc[mi][ni] = __builtin_amdgcn_mfma_f32_16x16x32_bf16(ah[mi], bh, acc[mi][ni], 0, 0, 0);
                    acc[mi][ni] = __builtin_amdgcn_mfma_f32_16x16x32_bf16(ah[mi], bl, acc[mi][ni], 0, 0, 0);
                    acc[mi][ni] = __builtin_amdgcn_mfma_f32_16x16x32_bf16(al[mi], bh, acc[mi][ni], 0, 0, 0);
                }
            }
        }
        __syncthreads();
    }

    // ---- epilogue: bias add + scatter rows ----
    const int g = lane >> 4, rl = lane & 15;
    float bv[4];
#pragma unroll
    for (int ni = 0; ni < 4; ++ni)
        bv[ni] = bias[(size_t)e * DOUT + n0 + wn * 64 + ni * 16 + rl];
#pragma unroll
    for (int mi = 0; mi < 4; ++mi) {
#pragma unroll
        for (int j = 0; j < 4; ++j) {
            int rm = m0 + wm * 64 + mi * 16 + g * 4 + j;
            if (rm < cnt) {
                int s = sorted[start + rm];
                float* orow = out + (size_t)s * DOUT + n0 + wn * 64 + rl;
#pragma unroll
                for (int ni = 0; ni < 4; ++ni)
                    orow[ni * 16] = acc[mi][ni][j] + bv[ni];
            }
        }
    }
}

extern "C" void kernel_launch(void* const* d_in, const int* in_sizes, int n_in,
                              void* d_out, int out_size, void* d_ws, size_t ws_size,
                              hipStream_t stream) {
    const float* xs      = (const float*)d_in[0];
    const float* mxs     = (const float*)d_in[1];
    const int*   actions = (const int*)d_in[2];
    const float* W       = (const float*)d_in[3];
    const float* b       = (const float*)d_in[4];
    float* out = (float*)d_out;

    int* ws_i   = (int*)d_ws;
    int* offs   = ws_i;         // NEXP+1
    int* sorted = ws_i + 32;    // BATCH

    sort_kernel<<<1, 256, 0, stream>>>(actions, mxs,
                                       out + (size_t)BATCH * DOUT, offs, sorted);

    dim3 grid(DOUT / BN, NEXP, BATCH / BM);
    gemm_kernel<<<grid, 256, 0, stream>>>(xs, W, b, offs, sorted, out);
}